// Round 1
// baseline (402.256 us; speedup 1.0000x reference)
//
#include <hip/hip_runtime.h>

#define NB 256
#define NL 512
#define NI 32
#define NH 16
#define NG 64
#define SIGD 4368

// ---------------- K1: input projection xw[b][t][g] = X[b,t,:]·W_ih[g,:] + b_ih[g] + b_hh[g]
__global__ __launch_bounds__(256) void k_xw(const float* __restrict__ X,
    const float* __restrict__ Wih, const float* __restrict__ bih,
    const float* __restrict__ bhh, float* __restrict__ xw) {
  int idx = blockIdx.x * 256 + threadIdx.x;   // 256*512*64 total
  int g = idx & 63;
  int bt = idx >> 6;                          // b*512 + t
  const float* xr = X + (size_t)bt * NI;
  const float* wr = Wih + g * NI;
  float acc = bih[g] + bhh[g];
#pragma unroll
  for (int i = 0; i < NI; i += 4) {
    float4 xv = *(const float4*)(xr + i);
    float4 wv = *(const float4*)(wr + i);
    acc += xv.x * wv.x;
    acc += xv.y * wv.y;
    acc += xv.z * wv.z;
    acc += xv.w * wv.w;
  }
  xw[idx] = acc;
}

// ---------------- K2: fused LSTM (wave 0) + chunked signature (8 waves) + tree combine in LDS
__global__ __launch_bounds__(512) void k_main(const float* __restrict__ xw,
    const float* __restrict__ Whh, float* __restrict__ sig) {
  // LDS layout (floats):
  //   [0, 8192)    : h rows (512 x 16)           -- phases A,B
  //   [0, 4352)    : combine slot0  (S2 256 | S3 4096 swizzled)   -- phase C (overlays h)
  //   [4352, 8704) : combine slot1                                -- phase C
  //   [8704, 8848) : 9 saved boundary rows (9 x 16)
  __shared__ __align__(16) float sm[8848];
  float* smh = sm;
  float* bnd = sm + 8704;
  int tid = threadIdx.x;
  int wv = tid >> 6;
  int ln = tid & 63;
  int b = blockIdx.x;

  // ---- Phase A: LSTM on wave 0; lane = gate g, gate type = ln>>4 (i,f,g,o), unit j = ln&15
  if (wv == 0) {
    const float* xg = xw + (size_t)b * NL * NG + ln;
    float w[NH];
#pragma unroll
    for (int q = 0; q < 4; ++q) {
      float4 v = *(const float4*)(Whh + ln * NH + 4 * q);
      w[4*q+0] = v.x; w[4*q+1] = v.y; w[4*q+2] = v.z; w[4*q+3] = v.w;
    }
    const bool isg = ((ln >> 4) == 2);
    const float K  = isg ? 2.885390082f : -1.442695041f; // exp2 scale: tanh vs sigmoid
    const float Av = isg ? -2.0f : 1.0f;
    const float Bv = isg ? 1.0f : 0.0f;
    float c = 0.0f, hval = 0.0f;
    float pre[8];
#pragma unroll
    for (int k = 0; k < 8; ++k) pre[k] = xg[k * NG];
    for (int tb = 0; tb < NL; tb += 8) {
#pragma unroll
      for (int k = 0; k < 8; ++k) {
        int t = tb + k;
        float a0 = pre[k], a1 = 0.f, a2 = 0.f, a3 = 0.f;
#pragma unroll
        for (int j = 0; j < NH; j += 4) {
          a0 += __shfl(hval, j + 0) * w[j + 0];
          a1 += __shfl(hval, j + 1) * w[j + 1];
          a2 += __shfl(hval, j + 2) * w[j + 2];
          a3 += __shfl(hval, j + 3) * w[j + 3];
        }
        int tn = t + 8;
        if (tn < NL) pre[k] = xg[tn * NG];   // 8-deep prefetch keeps HBM latency off chain
        float acc = (a0 + a1) + (a2 + a3);
        // sigmoid(x)=rcp(1+2^(-1.4427x)) ; tanh(x)=1-2*rcp(1+2^(2.8854x))
        float e = exp2f(K * acc);
        float r = __builtin_amdgcn_rcpf(1.0f + e);
        float val = Av * r + Bv;
        int j0 = ln & 15;
        float iv = __shfl(val, j0);
        float fv = __shfl(val, j0 + 16);
        float gv = __shfl(val, j0 + 32);
        float ov = __shfl(val, j0 + 48);
        c = fv * c + iv * gv;
        float e2 = exp2f(2.885390082f * c);
        float tc = 1.0f - 2.0f * __builtin_amdgcn_rcpf(1.0f + e2);
        hval = ov * tc;
        if (ln < NH) smh[t * NH + ln] = hval;
      }
    }
  }
  __syncthreads();

  // ---- Phase B: chunk signatures. Wave w: increments [64w, min(64w+64,511)).
  // Lane ln owns S3[a][b][c] for a=4m+(ln>>4), b=ln&15, c=0..15; S2[a][b] same (a,b).
  const int bi = ln & 15;
  const int hi = ln >> 4;
  int ts = 64 * wv;
  int te = min(ts + 64, NL - 1);
  float s3[4][16];
  float s2[4] = {0.f, 0.f, 0.f, 0.f};
#pragma unroll
  for (int m = 0; m < 4; ++m)
#pragma unroll
    for (int cc = 0; cc < 16; ++cc) s3[m][cc] = 0.f;
  float hc[16];
#pragma unroll
  for (int q = 0; q < 4; ++q) {
    float4 v = *(const float4*)(smh + ts * NH + 4 * q);
    hc[4*q+0]=v.x; hc[4*q+1]=v.y; hc[4*q+2]=v.z; hc[4*q+3]=v.w;
  }
  float hcb = smh[ts * NH + bi];
  float hca[4], h0a[4];
#pragma unroll
  for (int m = 0; m < 4; ++m) { hca[m] = smh[ts * NH + 4 * m + hi]; h0a[m] = hca[m]; }
  for (int t = ts; t < te; ++t) {
    const float* rn = smh + (t + 1) * NH;
    float hn[16];
#pragma unroll
    for (int q = 0; q < 4; ++q) {
      float4 v = *(const float4*)(rn + 4 * q);
      hn[4*q+0]=v.x; hn[4*q+1]=v.y; hn[4*q+2]=v.z; hn[4*q+3]=v.w;
    }
    float hnb = rn[bi];
    float d[16];
#pragma unroll
    for (int cc = 0; cc < 16; ++cc) d[cc] = hn[cc] - hc[cc];
    float db = hnb - hcb;
    float P[4];
#pragma unroll
    for (int m = 0; m < 4; ++m) {
      float hna = rn[4 * m + hi];
      float da = hna - hca[m];
      float s1 = hca[m] - h0a[m];                      // S1[a] pre-increment (telescoping)
      P[m] = s2[m] + db * (0.5f * s1 + 0.166666666667f * da);
      s2[m] += db * (s1 + 0.5f * da);                  // S2 += e2 + S1(x)e1
      hca[m] = hna;
    }
#pragma unroll
    for (int m = 0; m < 4; ++m)
#pragma unroll
      for (int cc = 0; cc < 16; ++cc)
        s3[m][cc] += P[m] * d[cc];                     // S3 += e3 + S2(x)e1 + S1(x)e2
#pragma unroll
    for (int cc = 0; cc < 16; ++cc) hc[cc] = hn[cc];
    hcb = hnb;
  }
  __syncthreads();

  // save boundary rows h[min(64k,511)] (k=0..8) before slots overwrite the h region
  if (tid < 144) {
    int k = tid >> 4, j = tid & 15;
    int row = min(64 * k, NL - 1);
    bnd[tid] = smh[row * NH + j];
  }
  __syncthreads();

  // ---- Phase C: Chen tree-combine via 2 LDS slots. Slot: S2[256] then S3[4096] XOR-swizzled.
  float* slot0 = sm;
  float* slot1 = sm + 4352;
  auto writeSlot = [&](float* slot) {
#pragma unroll
    for (int m = 0; m < 4; ++m) slot[64 * m + ln] = s2[m];  // index == a*16+b
    float* s3s = slot + 256;
#pragma unroll
    for (int m = 0; m < 4; ++m)
#pragma unroll
      for (int cc = 0; cc < 16; ++cc)
        s3s[64 * ln + ((m * 16 + cc) ^ (ln & 31))] = s3[m][cc];
  };
  // A (regs) <- A ⊗ B (slot). Segments in bnd-row indices: A=[as,ae], B=[bs,be] (ae==bs).
  auto combineSlot = [&](const float* slot, int as_, int ae_, int bs_, int be_) {
    const float* s2b = slot;
    const float* s3b = slot + 256;
    float s1b[16];
#pragma unroll
    for (int cc = 0; cc < 16; ++cc) s1b[cc] = bnd[be_ * 16 + cc] - bnd[bs_ * 16 + cc];
    float s1bb = bnd[be_ * 16 + bi] - bnd[bs_ * 16 + bi];
    float s1aa[4];
#pragma unroll
    for (int m = 0; m < 4; ++m) {
      int a = 4 * m + hi;
      s1aa[m] = bnd[ae_ * 16 + a] - bnd[as_ * 16 + a];
    }
    float row[16];
#pragma unroll
    for (int cc = 0; cc < 16; ++cc) row[cc] = s2b[bi * 16 + cc];
#pragma unroll
    for (int m = 0; m < 4; ++m) {
      float s2bo = s2b[64 * m + ln];
#pragma unroll
      for (int cc = 0; cc < 16; ++cc)
        s3[m][cc] += s3b[64 * ln + ((m * 16 + cc) ^ (ln & 31))]
                   + s2[m] * s1b[cc] + s1aa[m] * row[cc];   // uses OLD s2 (S2a)
      s2[m] += s2bo + s1aa[m] * s1bb;
    }
  };
  // Round 1a: (0,1) and (2,3)
  if (wv == 1) writeSlot(slot0);
  if (wv == 3) writeSlot(slot1);
  __syncthreads();
  if (wv == 0) combineSlot(slot0, 0, 1, 1, 2);
  if (wv == 2) combineSlot(slot1, 2, 3, 3, 4);
  __syncthreads();
  // Round 1b: (4,5) and (6,7)
  if (wv == 5) writeSlot(slot0);
  if (wv == 7) writeSlot(slot1);
  __syncthreads();
  if (wv == 4) combineSlot(slot0, 4, 5, 5, 6);
  if (wv == 6) combineSlot(slot1, 6, 7, 7, 8);
  __syncthreads();
  // Round 2: (01,23) and (45,67)
  if (wv == 2) writeSlot(slot0);
  if (wv == 6) writeSlot(slot1);
  __syncthreads();
  if (wv == 0) combineSlot(slot0, 0, 2, 2, 4);
  if (wv == 4) combineSlot(slot1, 4, 6, 6, 8);
  __syncthreads();
  // Round 3: (0123, 4567)
  if (wv == 4) writeSlot(slot0);
  __syncthreads();
  if (wv == 0) {
    combineSlot(slot0, 0, 4, 4, 8);
    // write sig[b] = [S1(16) | S2(256) | S3(4096)]
    float* sg = sig + (size_t)b * SIGD;
    if (ln < 16) sg[ln] = bnd[8 * 16 + ln] - bnd[ln];   // S1 = h[511]-h[0]
#pragma unroll
    for (int m = 0; m < 4; ++m) sg[16 + 64 * m + ln] = s2[m];
#pragma unroll
    for (int m = 0; m < 4; ++m) {
#pragma unroll
      for (int q = 0; q < 4; ++q) {
        float4 v;
        v.x = s3[m][4*q+0]; v.y = s3[m][4*q+1]; v.z = s3[m][4*q+2]; v.w = s3[m][4*q+3];
        *(float4*)(sg + 272 + 1024 * m + 256 * hi + 16 * bi + 4 * q) = v;
      }
    }
  }
}

// ---------------- K3: out[b][o] = sig[b]·fc_w[o] + fc_b[o]
__global__ __launch_bounds__(64) void k_fc(const float* __restrict__ sig,
    const float* __restrict__ fcw, const float* __restrict__ fcb,
    float* __restrict__ out) {
  int b = blockIdx.x;
  int ln = threadIdx.x;
  const float* sg = sig + (size_t)b * SIGD;
  float acc[10];
#pragma unroll
  for (int o = 0; o < 10; ++o) acc[o] = 0.f;
  for (int k = ln; k < SIGD; k += 64) {
    float s = sg[k];
#pragma unroll
    for (int o = 0; o < 10; ++o) acc[o] += s * fcw[o * SIGD + k];
  }
#pragma unroll
  for (int o = 0; o < 10; ++o) {
    float v = acc[o];
#pragma unroll
    for (int off = 32; off > 0; off >>= 1) v += __shfl_down(v, off);
    if (ln == 0) out[b * 10 + o] = v + fcb[o];
  }
}

extern "C" void kernel_launch(void* const* d_in, const int* in_sizes, int n_in,
                              void* d_out, int out_size, void* d_ws, size_t ws_size,
                              hipStream_t stream) {
  const float* X   = (const float*)d_in[0];
  const float* Wih = (const float*)d_in[1];
  const float* Whh = (const float*)d_in[2];
  const float* bih = (const float*)d_in[3];
  const float* bhh = (const float*)d_in[4];
  const float* fcw = (const float*)d_in[5];
  const float* fcb = (const float*)d_in[6];
  float* out = (float*)d_out;
  float* xw  = (float*)d_ws;                       // 256*512*64 floats = 33.5 MB
  float* sig = xw + (size_t)NB * NL * NG;          // 256*4368 floats  = 4.5 MB

  k_xw  <<<(NB * NL * NG) / 256, 256, 0, stream>>>(X, Wih, bih, bhh, xw);
  k_main<<<NB, 512, 0, stream>>>(xw, Whh, sig);
  k_fc  <<<NB, 64, 0, stream>>>(sig, fcw, fcb, out);
}

// Round 2
// 258.584 us; speedup vs baseline: 1.5556x; 1.5556x over previous
//
#include <hip/hip_runtime.h>

#define NB 256
#define NL 512
#define NI 32
#define NH 16
#define NG 64
#define SIGD 4368

__device__ __forceinline__ float RL(float v, int lane) {
  return __builtin_bit_cast(float, __builtin_amdgcn_readlane(__builtin_bit_cast(int, v), lane));
}
template<int CTRL>
__device__ __forceinline__ float QB(float v) {
  // quad_perm broadcast within each 4-lane quad (VALU DPP, no LDS)
  return __builtin_bit_cast(float, __builtin_amdgcn_update_dpp(
      0, __builtin_bit_cast(int, v), CTRL, 0xF, 0xF, true));
}
__device__ __forceinline__ int cutf(int k) {
  // segment cuts: 0,24,102,180,258,335,412,488,511 (small ends: they can't overlap LSTM)
  switch (k) {
    case 1: return 24;  case 2: return 102; case 3: return 180; case 4: return 258;
    case 5: return 335; case 6: return 412; case 7: return 488; case 8: return 511;
    default: return 0;
  }
}

// ---------------- K1: xw[b][t][g] = X[b,t,:]·W_ih[g,:] + b_ih[g] + b_hh[g]
// W register-stationary: wave = (sample, 128 timesteps), lane = gate.
__global__ __launch_bounds__(256) void k_xw(const float* __restrict__ X,
    const float* __restrict__ Wih, const float* __restrict__ bih,
    const float* __restrict__ bhh, float* __restrict__ xw) {
  int b = blockIdx.x;
  int wv = threadIdx.x >> 6;
  int g = threadIdx.x & 63;
  float w[NI];
#pragma unroll
  for (int i = 0; i < 8; ++i) {
    float4 v = *(const float4*)(Wih + g * NI + 4 * i);
    w[4*i+0] = v.x; w[4*i+1] = v.y; w[4*i+2] = v.z; w[4*i+3] = v.w;
  }
  float bias = bih[g] + bhh[g];
  const float* xb = X + (size_t)b * NL * NI;
  float* xo = xw + (size_t)b * NL * NG;
#pragma unroll 2
  for (int t = 128 * wv; t < 128 * (wv + 1); ++t) {
    const float4* xr = (const float4*)(xb + t * NI);
    float acc = bias;
#pragma unroll
    for (int i = 0; i < 8; ++i) {
      float4 xv = xr[i];                 // broadcast load: one cache line per row
      acc += xv.x * w[4*i+0];
      acc += xv.y * w[4*i+1];
      acc += xv.z * w[4*i+2];
      acc += xv.w * w[4*i+3];
    }
    xo[t * NG + g] = acc;                // coalesced 256B store
  }
}

// ---------------- K2: fused LSTM (wave 0) + overlapped chunked signature + tree combine
__global__ __launch_bounds__(512) void k_main(const float* __restrict__ xw,
    const float* __restrict__ Whh, float* __restrict__ sig) {
  // LDS layout (floats):
  //   [0, 8192)    : h rows (512 x 16)           -- phases A,B
  //   [0, 4352)    : combine slot0  (S2 256 | S3 4096 swizzled)   -- phase C (overlays h)
  //   [4352, 8704) : combine slot1                                -- phase C
  //   [8704, 8848) : 9 saved boundary rows (9 x 16)
  __shared__ __align__(16) float sm[8848];
  __shared__ int prog;
  float* smh = sm;
  float* bnd = sm + 8704;
  int tid = threadIdx.x;
  int wv = tid >> 6;
  int ln = tid & 63;
  int b = blockIdx.x;

  if (tid == 0) __hip_atomic_store(&prog, -1, __ATOMIC_RELAXED, __HIP_MEMORY_SCOPE_WORKGROUP);
  __syncthreads();

  // ---- Phase A (wave 0): LSTM, quad layout. lane = 4*unit + gate_type (0=i,1=f,2=g,3=o).
  if (wv == 0) {
    const int q = ln & 3;
    const int j = ln >> 2;
    const int gmem = q * 16 + j;               // memory gate index (i,f,g,o blocks of 16)
    const float* xg = xw + (size_t)b * NL * NG + gmem;
    float w[NH];
#pragma unroll
    for (int qq = 0; qq < 4; ++qq) {
      float4 v = *(const float4*)(Whh + gmem * NH + 4 * qq);
      w[4*qq+0] = v.x; w[4*qq+1] = v.y; w[4*qq+2] = v.z; w[4*qq+3] = v.w;
    }
    const bool isg = (q == 2);
    const float K  = isg ? 2.885390082f : -1.442695041f; // exp2 scale: tanh vs sigmoid
    const float Av = isg ? -2.0f : 1.0f;
    const float Bv = isg ? 1.0f : 0.0f;
    float c = 0.0f, hval = 0.0f;
    float pre[8];
#pragma unroll
    for (int k = 0; k < 8; ++k) pre[k] = xg[k * NG];
    for (int tb = 0; tb < NL; tb += 8) {
#pragma unroll
      for (int k = 0; k < 8; ++k) {
        int t = tb + k;
        // h·W_hh via v_readlane (unit j' lives on lane 4*j') — no LDS on the chain
        float a0 = pre[k], a1 = 0.f, a2 = 0.f, a3 = 0.f;
#pragma unroll
        for (int jj = 0; jj < 4; ++jj) {
          a0 += RL(hval, 16*jj + 0)  * w[4*jj + 0];
          a1 += RL(hval, 16*jj + 4)  * w[4*jj + 1];
          a2 += RL(hval, 16*jj + 8)  * w[4*jj + 2];
          a3 += RL(hval, 16*jj + 12) * w[4*jj + 3];
        }
        int tn = t + 8;
        if (tn < NL) pre[k] = xg[tn * NG];     // 8-deep global prefetch
        float acc = (a0 + a1) + (a2 + a3);
        float e = __builtin_amdgcn_exp2f(K * acc);
        float r = __builtin_amdgcn_rcpf(1.0f + e);
        float val = __builtin_fmaf(Av, r, Bv);
        // gather i,f,g,o of this quad's unit via DPP quad broadcasts (VALU)
        float iv = QB<0x00>(val);
        float fv = QB<0x55>(val);
        float gv = QB<0xAA>(val);
        float ov = QB<0xFF>(val);
        c = __builtin_fmaf(fv, c, iv * gv);
        float e2 = __builtin_amdgcn_exp2f(2.885390082f * c);
        float tc = __builtin_fmaf(-2.0f, __builtin_amdgcn_rcpf(1.0f + e2), 1.0f);
        hval = ov * tc;
        if (q == 0) smh[t * NH + j] = hval;
      }
      // publish progress: rows [0, tb+7] are in LDS (release orders the h stores)
      if (ln == 0) __hip_atomic_store(&prog, tb + 7, __ATOMIC_RELEASE, __HIP_MEMORY_SCOPE_WORKGROUP);
    }
  }

  // ---- Phase B: chunk signatures, overlapped with phase A via spin on prog.
  // Lane ln owns S3[a][b][c] for a=4m+(ln>>4), b=ln&15, c=0..15; S2[a][b] same (a,b).
  const int bi = ln & 15;
  const int hi = ln >> 4;
  int ts = cutf(wv);
  int te = cutf(wv + 1);
  while (__hip_atomic_load(&prog, __ATOMIC_ACQUIRE, __HIP_MEMORY_SCOPE_WORKGROUP) < te)
    __builtin_amdgcn_s_sleep(2);

  float s3[4][16];
  float s2[4] = {0.f, 0.f, 0.f, 0.f};
#pragma unroll
  for (int m = 0; m < 4; ++m)
#pragma unroll
    for (int cc = 0; cc < 16; ++cc) s3[m][cc] = 0.f;
  float hc[16];
#pragma unroll
  for (int qq = 0; qq < 4; ++qq) {
    float4 v = *(const float4*)(smh + ts * NH + 4 * qq);
    hc[4*qq+0]=v.x; hc[4*qq+1]=v.y; hc[4*qq+2]=v.z; hc[4*qq+3]=v.w;
  }
  float hcb = smh[ts * NH + bi];
  float hca[4], h0a[4];
#pragma unroll
  for (int m = 0; m < 4; ++m) { hca[m] = smh[ts * NH + 4 * m + hi]; h0a[m] = hca[m]; }
  for (int t = ts; t < te; ++t) {
    const float* rn = smh + (t + 1) * NH;
    float hn[16];
#pragma unroll
    for (int qq = 0; qq < 4; ++qq) {
      float4 v = *(const float4*)(rn + 4 * qq);
      hn[4*qq+0]=v.x; hn[4*qq+1]=v.y; hn[4*qq+2]=v.z; hn[4*qq+3]=v.w;
    }
    float hnb = rn[bi];
    float d[16];
#pragma unroll
    for (int cc = 0; cc < 16; ++cc) d[cc] = hn[cc] - hc[cc];
    float db = hnb - hcb;
    float P[4];
#pragma unroll
    for (int m = 0; m < 4; ++m) {
      float hna = rn[4 * m + hi];
      float da = hna - hca[m];
      float s1 = hca[m] - h0a[m];                      // S1[a] pre-increment (telescoping)
      P[m] = s2[m] + db * (0.5f * s1 + 0.166666666667f * da);
      s2[m] += db * (s1 + 0.5f * da);                  // S2 += e2 + S1(x)e1
      hca[m] = hna;
    }
#pragma unroll
    for (int m = 0; m < 4; ++m)
#pragma unroll
      for (int cc = 0; cc < 16; ++cc)
        s3[m][cc] += P[m] * d[cc];                     // S3 += e3 + S2(x)e1 + S1(x)e2
#pragma unroll
    for (int cc = 0; cc < 16; ++cc) hc[cc] = hn[cc];
    hcb = hnb;
  }
  __syncthreads();

  // save boundary rows h[cut(k)] (k=0..8) before slots overwrite the h region
  if (tid < 144) {
    int k = tid >> 4, j = tid & 15;
    bnd[tid] = smh[cutf(k) * NH + j];
  }
  __syncthreads();

  // ---- Phase C: Chen tree-combine via 2 LDS slots. Slot: S2[256] then S3[4096] XOR-swizzled.
  float* slot0 = sm;
  float* slot1 = sm + 4352;
  auto writeSlot = [&](float* slot) {
#pragma unroll
    for (int m = 0; m < 4; ++m) slot[64 * m + ln] = s2[m];  // index == a*16+b
    float* s3s = slot + 256;
#pragma unroll
    for (int m = 0; m < 4; ++m)
#pragma unroll
      for (int cc = 0; cc < 16; ++cc)
        s3s[64 * ln + ((m * 16 + cc) ^ (ln & 31))] = s3[m][cc];
  };
  // A (regs) <- A ⊗ B (slot). Segments in bnd-row indices: A=[as,ae], B=[bs,be] (ae==bs).
  auto combineSlot = [&](const float* slot, int as_, int ae_, int bs_, int be_) {
    const float* s2b = slot;
    const float* s3b = slot + 256;
    float s1b[16];
#pragma unroll
    for (int cc = 0; cc < 16; ++cc) s1b[cc] = bnd[be_ * 16 + cc] - bnd[bs_ * 16 + cc];
    float s1bb = bnd[be_ * 16 + bi] - bnd[bs_ * 16 + bi];
    float s1aa[4];
#pragma unroll
    for (int m = 0; m < 4; ++m) {
      int a = 4 * m + hi;
      s1aa[m] = bnd[ae_ * 16 + a] - bnd[as_ * 16 + a];
    }
    float row[16];
#pragma unroll
    for (int cc = 0; cc < 16; ++cc) row[cc] = s2b[bi * 16 + cc];
#pragma unroll
    for (int m = 0; m < 4; ++m) {
      float s2bo = s2b[64 * m + ln];
#pragma unroll
      for (int cc = 0; cc < 16; ++cc)
        s3[m][cc] += s3b[64 * ln + ((m * 16 + cc) ^ (ln & 31))]
                   + s2[m] * s1b[cc] + s1aa[m] * row[cc];   // uses OLD s2 (S2a)
      s2[m] += s2bo + s1aa[m] * s1bb;
    }
  };
  // Round 1a: (0,1) and (2,3)
  if (wv == 1) writeSlot(slot0);
  if (wv == 3) writeSlot(slot1);
  __syncthreads();
  if (wv == 0) combineSlot(slot0, 0, 1, 1, 2);
  if (wv == 2) combineSlot(slot1, 2, 3, 3, 4);
  __syncthreads();
  // Round 1b: (4,5) and (6,7)
  if (wv == 5) writeSlot(slot0);
  if (wv == 7) writeSlot(slot1);
  __syncthreads();
  if (wv == 4) combineSlot(slot0, 4, 5, 5, 6);
  if (wv == 6) combineSlot(slot1, 6, 7, 7, 8);
  __syncthreads();
  // Round 2: (01,23) and (45,67)
  if (wv == 2) writeSlot(slot0);
  if (wv == 6) writeSlot(slot1);
  __syncthreads();
  if (wv == 0) combineSlot(slot0, 0, 2, 2, 4);
  if (wv == 4) combineSlot(slot1, 4, 6, 6, 8);
  __syncthreads();
  // Round 3: (0123, 4567)
  if (wv == 4) writeSlot(slot0);
  __syncthreads();
  if (wv == 0) {
    combineSlot(slot0, 0, 4, 4, 8);
    // write sig[b] = [S1(16) | S2(256) | S3(4096)]
    float* sg = sig + (size_t)b * SIGD;
    if (ln < 16) sg[ln] = bnd[8 * 16 + ln] - bnd[ln];   // S1 = h[511]-h[0]
#pragma unroll
    for (int m = 0; m < 4; ++m) sg[16 + 64 * m + ln] = s2[m];
#pragma unroll
    for (int m = 0; m < 4; ++m) {
#pragma unroll
      for (int qq = 0; qq < 4; ++qq) {
        float4 v;
        v.x = s3[m][4*qq+0]; v.y = s3[m][4*qq+1]; v.z = s3[m][4*qq+2]; v.w = s3[m][4*qq+3];
        *(float4*)(sg + 272 + 1024 * m + 256 * hi + 16 * bi + 4 * qq) = v;
      }
    }
  }
}

// ---------------- K3: out[b][o] = sig[b]·fc_w[o] + fc_b[o]
__global__ __launch_bounds__(64) void k_fc(const float* __restrict__ sig,
    const float* __restrict__ fcw, const float* __restrict__ fcb,
    float* __restrict__ out) {
  int b = blockIdx.x;
  int ln = threadIdx.x;
  const float* sg = sig + (size_t)b * SIGD;
  float acc[10];
#pragma unroll
  for (int o = 0; o < 10; ++o) acc[o] = 0.f;
  for (int k = ln; k < SIGD; k += 64) {
    float s = sg[k];
#pragma unroll
    for (int o = 0; o < 10; ++o) acc[o] += s * fcw[o * SIGD + k];
  }
#pragma unroll
  for (int o = 0; o < 10; ++o) {
    float v = acc[o];
#pragma unroll
    for (int off = 32; off > 0; off >>= 1) v += __shfl_down(v, off);
    if (ln == 0) out[b * 10 + o] = v + fcb[o];
  }
}

extern "C" void kernel_launch(void* const* d_in, const int* in_sizes, int n_in,
                              void* d_out, int out_size, void* d_ws, size_t ws_size,
                              hipStream_t stream) {
  const float* X   = (const float*)d_in[0];
  const float* Wih = (const float*)d_in[1];
  const float* Whh = (const float*)d_in[2];
  const float* bih = (const float*)d_in[3];
  const float* bhh = (const float*)d_in[4];
  const float* fcw = (const float*)d_in[5];
  const float* fcb = (const float*)d_in[6];
  float* out = (float*)d_out;
  float* xw  = (float*)d_ws;                       // 256*512*64 floats = 33.5 MB
  float* sig = xw + (size_t)NB * NL * NG;          // 256*4368 floats  = 4.5 MB

  k_xw  <<<NB, 256, 0, stream>>>(X, Wih, bih, bhh, xw);
  k_main<<<NB, 512, 0, stream>>>(xw, Whh, sig);
  k_fc  <<<NB, 64, 0, stream>>>(sig, fcw, fcb, out);
}